// Round 9
// baseline (254.278 us; speedup 1.0000x reference)
//
#include <hip/hip_runtime.h>
#include <cstddef>

// StreamingISTFT fully fused: staged denorm -> FFT32(k2) -> LDS -> FFT32(k1)
// -> window -> LDS frame tile -> overlap-add -> coalesced stores.
// B=8, F=1024(+Nyquist), T=2048, HOP=512, L=2048.
// irfft(2048) = complex IFFT(1024) (real-packing); IFFT(1024) = 32x32 four-step.
//
// R8:  XCD-aware remap: FETCH 446->67 MB.
// R11: staged float4 input: 100->85 us.
// R12/R13: phase-splitting -> 115-117 us REGRESSIONS.
// R14: simple structure + twiddle recurrence: 85 us.
// R15: interleaved LDS: ~neutral on LDS path; OLA float2 atomics de-coalesced
//      (WRITE +24.5 MB = exactly the atomic columns) -> 88.7 us. Reverted OLA.
// R16: TT=16 / 512-thread blocks. Cross-round invariant: dur ~85 us at
//      8-16 static waves/CU, VALUBusy 35-41% -> LDS-per-wave never improved.
//      Doubling tile width amortizes the same ~66 KB tiles over 8 waves:
//      LDS_Block stays 67584 (r-split X + frame-split OLA, both proven
//      cost-free) => 2 blocks/CU x 8 waves = 16 waves/CU (2x). Also: atomic
//      columns per output halve, OLA is a single 512-wide column pass
//      (consecutive scalar pattern -- undoes R15's WRITE regression),
//      barriers per unit work halve.

#define TDIM 2048
#define FDIM 1024
#define TT 16                   // t-columns per block
#define NTHR 512
#define NTOT (512 * 2048)       // output samples per batch
#define FSTR 2054               // frame tile row stride
#define XPAD 264                // float2 per k1 row in half-X (16*16 + 8 pad)

static constexpr int kBREV[32] = {0,16,8,24,4,20,12,28,2,18,10,26,6,22,14,30,
                                  1,17,9,25,5,21,13,29,3,19,11,27,7,23,15,31};
// e^{+2*pi*i*r/32}, r=0..15 (inverse-transform sign)
static constexpr float kTR[16] = {
  1.0f, 0.98078528040323044f, 0.92387953251128674f, 0.83146961230254524f,
  0.70710678118654757f, 0.55557023301960218f, 0.38268343236508978f, 0.19509032201612825f,
  0.0f, -0.19509032201612825f, -0.38268343236508978f, -0.55557023301960218f,
  -0.70710678118654757f, -0.83146961230254524f, -0.92387953251128674f, -0.98078528040323044f};
static constexpr float kTI[16] = {
  0.0f, 0.19509032201612825f, 0.38268343236508978f, 0.55557023301960218f,
  0.70710678118654757f, 0.83146961230254524f, 0.92387953251128674f, 0.98078528040323044f,
  1.0f, 0.98078528040323044f, 0.92387953251128674f, 0.83146961230254524f,
  0.70710678118654757f, 0.55557023301960218f, 0.38268343236508978f, 0.19509032201612825f};
// 64th roots of unity: kCC[k2]=cos(2*pi*k2/64), kSS[k2]=sin(2*pi*k2/64)
static constexpr float kCC[32] = {
  1.0f, 0.99518472667219693f, 0.98078528040323044f, 0.95694033573220882f,
  0.92387953251128674f, 0.88192126434835505f, 0.83146961230254524f, 0.77301045336273699f,
  0.70710678118654757f, 0.63439328416364549f, 0.55557023301960218f, 0.47139673682599764f,
  0.38268343236508978f, 0.29028467725446233f, 0.19509032201612825f, 0.098017140329560604f,
  0.0f, -0.098017140329560604f, -0.19509032201612825f, -0.29028467725446233f,
  -0.38268343236508978f, -0.47139673682599764f, -0.55557023301960218f, -0.63439328416364549f,
  -0.70710678118654757f, -0.77301045336273699f, -0.83146961230254524f, -0.88192126434835505f,
  -0.92387953251128674f, -0.95694033573220882f, -0.98078528040323044f, -0.99518472667219693f};
static constexpr float kSS[32] = {
  0.0f, 0.098017140329560604f, 0.19509032201612825f, 0.29028467725446233f,
  0.38268343236508978f, 0.47139673682599764f, 0.55557023301960218f, 0.63439328416364549f,
  0.70710678118654757f, 0.77301045336273699f, 0.83146961230254524f, 0.88192126434835505f,
  0.92387953251128674f, 0.95694033573220882f, 0.98078528040323044f, 0.99518472667219693f,
  1.0f, 0.99518472667219693f, 0.98078528040323044f, 0.95694033573220882f,
  0.92387953251128674f, 0.88192126434835505f, 0.83146961230254524f, 0.77301045336273699f,
  0.70710678118654757f, 0.63439328416364549f, 0.55557023301960218f, 0.47139673682599764f,
  0.38268343236508978f, 0.29028467725446233f, 0.19509032201612825f, 0.098017140329560604f};

template <int H>
__device__ __forceinline__ void fft32_stage(float ar[32], float ai[32]) {
  constexpr int TSTEP = 16 / H;
  #pragma unroll
  for (int g = 0; g < 32; g += 2 * H) {
    #pragma unroll
    for (int j = 0; j < H; ++j) {
      const float twr = kTR[j * TSTEP];
      const float twi = kTI[j * TSTEP];
      const int i0 = g + j, i1 = i0 + H;
      const float tr = twr * ar[i1] - twi * ai[i1];
      const float ti = twr * ai[i1] + twi * ar[i1];
      ar[i1] = ar[i0] - tr; ai[i1] = ai[i0] - ti;
      ar[i0] += tr;         ai[i0] += ti;
    }
  }
}

// In-register radix-2 DIT FFT32 (inverse sign). Input bit-reversed; out natural.
__device__ __forceinline__ void ifft32_core(float ar[32], float ai[32]) {
  fft32_stage<1>(ar, ai);
  fft32_stage<2>(ar, ai);
  fft32_stage<4>(ar, ai);
  fft32_stage<8>(ar, ai);
  fft32_stage<16>(ar, ai);
}

// |v|^(2*PE) * KS via native v_log_f32 + v_exp_f32. v=0 -> 0: ok.
__device__ __forceinline__ float pow_gain(float v, float PE, float KS) {
  return KS * __builtin_amdgcn_exp2f(PE * __builtin_amdgcn_logf(v));
}

__device__ __forceinline__ void denorm4(float4& r, float4& i, float PE, float KS) {
  float g;
  g = pow_gain(r.x * r.x + i.x * i.x, PE, KS); r.x *= g; i.x *= g;
  g = pow_gain(r.y * r.y + i.y * i.y, PE, KS); r.y *= g; i.y *= g;
  g = pow_gain(r.z * r.z + i.z * i.z, PE, KS); r.z *= g; i.z *= g;
  g = pow_gain(r.w * r.w + i.w * i.w, PE, KS); r.w *= g; i.w *= g;
}

// superchunk slot -> global row. SC0: slots [0,256)=rows [0,256), slots
// [256,512)=rows [768,1024), slot 512=row 256. SC1: slot s=row s+256,
// slot 512=row 768.  (Proven R11/R14/R15.)
template <int SC>
__device__ __forceinline__ int slot_row(int s) {
  return (SC == 0) ? (s < 256 ? s : s + 512) : (s + 256);
}

// Interleaved staging, TT=16: Sri[slot*32 + 2*t + {0,1}] = {re,im}. 513 slots.
// Pack reads: start bank = 2*tl (q drops out) -> exactly the b64 floor.
// Stage-1 pack+bitrev for one superchunk's 16 k2 values. Mirror-slot
// identities (row-index based, TT-independent; proven R11-R15):
// slotm(q>0) = (32-q)+32*(15-u); slotm(q==0) = 32*(16-u) with SC0
// exceptions u=0 -> 0, u=8 -> 512.
template <int SC>
__device__ __forceinline__ void stage1_compute(const float* __restrict__ Sri,
                                               int q, int tl, float wc, float ws,
                                               float ar[32], float ai[32]) {
  #pragma unroll
  for (int u = 0; u < 16; ++u) {
    const int k2 = (SC == 0) ? (u < 8 ? u : u + 16) : (u + 8);
    const int slot = q + 32 * u;
    int slotm_zero = 32 * (16 - u);
    if (SC == 0 && u == 0) slotm_zero = 0;
    if (SC == 0 && u == 8) slotm_zero = 512;
    const int slotm_pos = (32 - q) + 32 * (15 - u);
    const int slotm = (q == 0) ? slotm_zero : slotm_pos;

    const float2 s1 = *(const float2*)(Sri + slot * 32 + 2 * tl);
    const float2 s2 = *(const float2*)(Sri + slotm * 32 + 2 * tl);
    // W[k] = (S1 + conj(S2)) + i*T*(S1 - conj(S2)),  T = e^{i pi k/1024}
    // T = e^{i pi q/1024} * e^{i pi k2/32}  (constant tables, 4 FMA)
    const float cs = wc * kCC[k2] - ws * kSS[k2];
    const float sn = ws * kCC[k2] + wc * kSS[k2];
    const float Pre = s1.x + s2.x, Pim = s1.y - s2.y;
    const float Qre = s1.x - s2.x, Qim = s1.y + s2.y;
    const float uu = cs * Qim + sn * Qre;
    const float vv = cs * Qre - sn * Qim;
    float wr = Pre - uu, wi = Pim + vv;
    if (q == 0 && k2 == 0) { wr = s1.x; wi = s1.x; }  // DC: Im dropped, Nyquist=0
    ar[kBREV[k2]] = wr; ai[kBREV[k2]] = wi;
  }
}

// Half-X (interleaved float2), TT=16: XH = k1*264 + rh*16 + t, rh in [0,16).
// 32*264 = 8448 float2 = 67584 B. Write banks (16q+2tl)%32, read banks
// (16*qh+2tl)%32 -> both exactly at the b64 floor (4 lanes/bank-pair).
#define XH(t, k1, rh) ((k1) * XPAD + (rh) * 16 + (t))

__global__ __launch_bounds__(NTHR) void istft_fused(const float* __restrict__ in,
                                                    const float* __restrict__ invw,
                                                    float* __restrict__ out) {
  __shared__ float buf[16896];          // 67584 B, three overlapped tenants:
  float* Sri = buf;                     //  staging (interleaved): [0,16416)
  float* Xc  = buf;                     //  half-X (float2): [0,16896)
  float* Fh  = buf;                     //  frame half (8 rows): [0,16432)

  const int tid = threadIdx.x;
  const int tl  = tid & 15;             // t within tile (0..15)
  const int q   = tid >> 4;             // k1 (stage 1) / r (stage 2), 0..31

  // XCD-aware remap (R8): each XCD owns 16 contiguous 16-wide t-tiles of one
  // batch (256 contiguous columns, same footprint as before).
  const int id   = blockIdx.x;          // 0..1023
  const int xcd  = id & 7;
  const int slot = id >> 3;             // 0..127
  const int b    = slot >> 4;           // 0..7
  const int tile = xcd * 16 + (slot & 15);  // 0..127
  const int t0   = tile * TT;

  const float* re_p = in + ((size_t)b * 2 + 0) * ((size_t)FDIM * TDIM);
  const float* im_p = in + ((size_t)b * 2 + 1) * ((size_t)FDIM * TDIM);

  const float KS = (float)(exp((-1.0 / 0.65) * log(0.06)) / 2048.0);
  const float PE = 7.0f / 26.0f;

  // pack twiddle base: e^{i*pi*q/1024}
  const float aq = 3.0679615757712824e-3f * (float)q;
  const float wc = __cosf(aq), ws = __sinf(aq);

  float ar[32], ai[32];

  // ---- Stage 1: superchunk A load/denorm/stage; B loads in flight ----
  // Task j (j=0..3): f = tid + 512*j, s = f>>2 (slot), cg = f&3 (t-quad).
  {
    float4 reA[4], imA[4];
    #pragma unroll
    for (int j = 0; j < 4; ++j) {
      const int f = tid + NTHR * j;
      const int s = f >> 2, cg = f & 3;
      const int row = slot_row<0>(s);
      reA[j] = *(const float4*)(re_p + (size_t)row * TDIM + t0 + 4 * cg);
      imA[j] = *(const float4*)(im_p + (size_t)row * TDIM + t0 + 4 * cg);
    }
    float4 exRe, exIm;                  // extra row 256 -> slot 512 (tid<4)
    if (tid < 4) {
      exRe = *(const float4*)(re_p + (size_t)256 * TDIM + t0 + 4 * tid);
      exIm = *(const float4*)(im_p + (size_t)256 * TDIM + t0 + 4 * tid);
    }
    #pragma unroll
    for (int j = 0; j < 4; ++j) {
      const int f = tid + NTHR * j;
      const int s = f >> 2, cg = f & 3;
      denorm4(reA[j], imA[j], PE, KS);
      const float4 w0 = {reA[j].x, imA[j].x, reA[j].y, imA[j].y};
      const float4 w1 = {reA[j].z, imA[j].z, reA[j].w, imA[j].w};
      *(float4*)(Sri + s * 32 + 8 * cg)     = w0;
      *(float4*)(Sri + s * 32 + 8 * cg + 4) = w1;
    }
    if (tid < 4) {
      denorm4(exRe, exIm, PE, KS);
      const float4 w0 = {exRe.x, exIm.x, exRe.y, exIm.y};
      const float4 w1 = {exRe.z, exIm.z, exRe.w, exIm.w};
      *(float4*)(Sri + 512 * 32 + 8 * tid)     = w0;
      *(float4*)(Sri + 512 * 32 + 8 * tid + 4) = w1;
    }

    // issue superchunk B global loads now (consumed after compute A)
    float4 reB[4], imB[4];
    #pragma unroll
    for (int j = 0; j < 4; ++j) {
      const int f = tid + NTHR * j;
      const int s = f >> 2, cg = f & 3;
      const int row = slot_row<1>(s);
      reB[j] = *(const float4*)(re_p + (size_t)row * TDIM + t0 + 4 * cg);
      imB[j] = *(const float4*)(im_p + (size_t)row * TDIM + t0 + 4 * cg);
    }
    float4 exReB, exImB;                // extra row 768 -> slot 512 (tid<4)
    if (tid < 4) {
      exReB = *(const float4*)(re_p + (size_t)768 * TDIM + t0 + 4 * tid);
      exImB = *(const float4*)(im_p + (size_t)768 * TDIM + t0 + 4 * tid);
    }
    __syncthreads();

    // compute superchunk A (k2 in [0,8) u [24,32))
    stage1_compute<0>(Sri, q, tl, wc, ws, ar, ai);
    __syncthreads();                    // all A reads done before B overwrites

    // stage superchunk B; compute (k2 in [8,24))
    #pragma unroll
    for (int j = 0; j < 4; ++j) {
      const int f = tid + NTHR * j;
      const int s = f >> 2, cg = f & 3;
      denorm4(reB[j], imB[j], PE, KS);
      const float4 w0 = {reB[j].x, imB[j].x, reB[j].y, imB[j].y};
      const float4 w1 = {reB[j].z, imB[j].z, reB[j].w, imB[j].w};
      *(float4*)(Sri + s * 32 + 8 * cg)     = w0;
      *(float4*)(Sri + s * 32 + 8 * cg + 4) = w1;
    }
    if (tid < 4) {
      denorm4(exReB, exImB, PE, KS);
      const float4 w0 = {exReB.x, exImB.x, exReB.y, exImB.y};
      const float4 w1 = {exReB.z, exImB.z, exReB.w, exImB.w};
      *(float4*)(Sri + 512 * 32 + 8 * tid)     = w0;
      *(float4*)(Sri + 512 * 32 + 8 * tid + 4) = w1;
    }
    __syncthreads();
    stage1_compute<1>(Sri, q, tl, wc, ws, ar, ai);
    __syncthreads();                    // staging dead; X may overwrite buf
  }

  // ---- FFT32 over k2 ----
  ifft32_core(ar, ai);

  // ---- Transpose through half-X (r-split), interleaved float2 ----
  // Inter-stage twiddle e^{2 pi i q r/1024} by incremental rotation carried
  // ACROSS both halves (31 steps total, err ~2e-6 << 0.0625 absmax).
  float zr[32], zi[32];
  {
    const float aq2 = 6.1359231515425649e-3f * (float)q;
    const float dc = __cosf(aq2), dsn = __sinf(aq2);
    float cs = 1.0f, sn = 0.0f;
    #pragma unroll
    for (int r = 0; r < 16; ++r) {      // half A: r in [0,16)
      const float2 xv = {cs * ar[r] - sn * ai[r], cs * ai[r] + sn * ar[r]};
      *(float2*)(Xc + 2 * XH(tl, q, r)) = xv;
      const float ncs = cs * dc - sn * dsn;
      sn = cs * dsn + sn * dc;
      cs = ncs;
    }
    __syncthreads();
    if (q < 16) {                       // waves 0-3 read their stage-2 input
      #pragma unroll
      for (int i = 0; i < 32; ++i) {    // bit-reversed k1 load order
        const float2 zv = *(const float2*)(Xc + 2 * XH(tl, kBREV[i], q));
        zr[i] = zv.x; zi[i] = zv.y;
      }
    }
    __syncthreads();
    #pragma unroll
    for (int r = 16; r < 32; ++r) {     // half B: r in [16,32), recurrence cont.
      const float2 xv = {cs * ar[r] - sn * ai[r], cs * ai[r] + sn * ar[r]};
      *(float2*)(Xc + 2 * XH(tl, q, r - 16)) = xv;
      const float ncs = cs * dc - sn * dsn;
      sn = cs * dsn + sn * dc;
      cs = ncs;
    }
    __syncthreads();
    if (q >= 16) {                      // waves 4-7 read their stage-2 input
      #pragma unroll
      for (int i = 0; i < 32; ++i) {
        const float2 zv = *(const float2*)(Xc + 2 * XH(tl, kBREV[i], q - 16));
        zr[i] = zv.x; zi[i] = zv.y;
      }
    }
    __syncthreads();                    // X dead; F tile may overwrite buf
  }

  // ---- Stage 2: FFT32 over k1 ----
  ifft32_core(zr, zi);

  // ---- Frame-split OLA: frames tt in [0,8) then [8,16) ----
  // frames[tl][l], l = 2*(q+32s)+{0,1}. Output col rel = t'-t0, rel 0..18.
  // Phase A: store rel 3..7, atomic rel 0..2, carry rel 8..10 (3 regs).
  // Phase B: store rel 8..15 (carry-completed), atomic rel 16..18.
  float* ob = out + (size_t)b * NTOT;
  float carry[3];

  if (tl < 8) {                         // F phase A: frames 0..7
    #pragma unroll
    for (int s = 0; s < 32; ++s) {
      const int l0 = 2 * q + 64 * s;
      const float2 w2 = *(const float2*)(invw + l0);
      const float2 fv = {zr[s] * w2.x, zi[s] * w2.y};
      *(float2*)(Fh + tl * FSTR + l0) = fv;
    }
  }
  __syncthreads();
  #pragma unroll
  for (int rel = 0; rel < 11; ++rel) {  // OLA A: contributors tt in [0,8)
    float v = 0.0f;
    #pragma unroll
    for (int c = 0; c < 4; ++c) {
      const int tt = rel - c;
      if (tt >= 0 && tt < 8) v += Fh[tt * FSTR + tid + 512 * c];
    }
    if (rel < 3)       atomicAdd(&ob[(t0 + rel) * 512 + tid], v);  // boundary
    else if (rel <= 7) ob[(t0 + rel) * 512 + tid] = v;             // complete
    else               carry[rel - 8] = v;                         // 8..10
  }
  __syncthreads();
  if (tl >= 8) {                        // F phase B: frames 8..15 at row tl-8
    #pragma unroll
    for (int s = 0; s < 32; ++s) {
      const int l0 = 2 * q + 64 * s;
      const float2 w2 = *(const float2*)(invw + l0);
      const float2 fv = {zr[s] * w2.x, zi[s] * w2.y};
      *(float2*)(Fh + (tl - 8) * FSTR + l0) = fv;
    }
  }
  __syncthreads();
  #pragma unroll
  for (int rel = 8; rel < 19; ++rel) {  // OLA B: contributors tt in [8,16)
    const int tp = t0 + rel;
    if (tp > 2047) continue;            // only rel>=16 of the last tile
    float v = (rel <= 10) ? carry[rel - 8] : 0.0f;
    #pragma unroll
    for (int c = 0; c < 4; ++c) {
      const int tt = rel - c;
      if (tt >= 8 && tt < 16) v += Fh[(tt - 8) * FSTR + tid + 512 * c];
    }
    const int n = tp * 512 + tid;
    if (rel <= 15) ob[n] = v;           // all 4 contributors seen in-block
    else atomicAdd(&ob[n], v);          // tile boundary: 2 writers
  }
}

extern "C" void kernel_launch(void* const* d_in, const int* in_sizes, int n_in,
                              void* d_out, int out_size, void* d_ws, size_t ws_size,
                              hipStream_t stream) {
  (void)in_sizes; (void)n_in; (void)d_ws; (void)ws_size;
  const float* in   = (const float*)d_in[0];
  const float* invw = (const float*)d_in[1];
  float* out = (float*)d_out;
  hipMemsetAsync(out, 0, (size_t)out_size * sizeof(float), stream);
  istft_fused<<<dim3(TDIM / TT * 8), NTHR, 0, stream>>>(in, invw, out);
}

// Round 10
// 228.911 us; speedup vs baseline: 1.1108x; 1.1108x over previous
//
#include <hip/hip_runtime.h>
#include <cstddef>

// StreamingISTFT fully fused: pair-load + denorm + Hermitian-pack at the
// LOADER -> staged W -> FFT32(k2) -> LDS -> FFT32(k1) -> window -> LDS frame
// tile -> overlap-add -> coalesced stores.
// B=8, F=1024(+Nyquist), T=2048, HOP=512, L=2048.
// irfft(2048) = complex IFFT(1024) (real-packing); IFFT(1024) = 32x32 four-step.
//
// R8:  XCD-aware remap: FETCH 446->67 MB.
// R11: staged float4 input: 100->85 us.
// R12/R13/R16: occupancy campaigns (quarter-split, dbuf pipeline, TT=16) all
//      REGRESSED 110-117 us. Occupancy never converts; floor = per-wave
//      critical path. R14 (simple full tiles + twiddle recurrence) = 85 us.
// R17: loader-side pack. Stage-1's serial chain was 64 latency-exposed b64
//      reads + ~14 dependent pack ops each. Mirror pack shares intermediates:
//      Wa=(Pre-u,Pim+v), Wb=(Pre+u,v-Pim) -- 2 extra ops. So threads load
//      mirror-PAIRS of rows (slots {c,512-c,128+c,384-c}; c=0: {0,128,256,
//      384,512}), pack during staging (hidden under VMEM latency), stage W.
//      Consumer: ONE b64 per k2, zero pack VALU, no mirror reads, no q=0
//      special case. LDS pack reads 64->32; ~450 VALU removed from the
//      barrier-serialized consumer phase. Self-pairs: k=0 DC (Wa=(re,re)),
//      k=512 (uniform formula, Wa==Wb). Staging stride 20: b128 writes
//      16B-aligned at bank floor; b64 reads at floor. Rest = R14 verbatim.

#define TDIM 2048
#define FDIM 1024
#define TT 8                    // t-columns per block
#define NTOT (512 * 2048)       // output samples per batch
#define SSTR 20                 // staging slot stride (floats); 513*20 fits buf

static constexpr int kBREV[32] = {0,16,8,24,4,20,12,28,2,18,10,26,6,22,14,30,
                                  1,17,9,25,5,21,13,29,3,19,11,27,7,23,15,31};
// e^{+2*pi*i*r/32}, r=0..15 (inverse-transform sign)
static constexpr float kTR[16] = {
  1.0f, 0.98078528040323044f, 0.92387953251128674f, 0.83146961230254524f,
  0.70710678118654757f, 0.55557023301960218f, 0.38268343236508978f, 0.19509032201612825f,
  0.0f, -0.19509032201612825f, -0.38268343236508978f, -0.55557023301960218f,
  -0.70710678118654757f, -0.83146961230254524f, -0.92387953251128674f, -0.98078528040323044f};
static constexpr float kTI[16] = {
  0.0f, 0.19509032201612825f, 0.38268343236508978f, 0.55557023301960218f,
  0.70710678118654757f, 0.83146961230254524f, 0.92387953251128674f, 0.98078528040323044f,
  1.0f, 0.98078528040323044f, 0.92387953251128674f, 0.83146961230254524f,
  0.70710678118654757f, 0.55557023301960218f, 0.38268343236508978f, 0.19509032201612825f};

template <int H>
__device__ __forceinline__ void fft32_stage(float ar[32], float ai[32]) {
  constexpr int TSTEP = 16 / H;
  #pragma unroll
  for (int g = 0; g < 32; g += 2 * H) {
    #pragma unroll
    for (int j = 0; j < H; ++j) {
      const float twr = kTR[j * TSTEP];
      const float twi = kTI[j * TSTEP];
      const int i0 = g + j, i1 = i0 + H;
      const float tr = twr * ar[i1] - twi * ai[i1];
      const float ti = twr * ai[i1] + twi * ar[i1];
      ar[i1] = ar[i0] - tr; ai[i1] = ai[i0] - ti;
      ar[i0] += tr;         ai[i0] += ti;
    }
  }
}

// In-register radix-2 DIT FFT32 (inverse sign). Input bit-reversed; out natural.
__device__ __forceinline__ void ifft32_core(float ar[32], float ai[32]) {
  fft32_stage<1>(ar, ai);
  fft32_stage<2>(ar, ai);
  fft32_stage<4>(ar, ai);
  fft32_stage<8>(ar, ai);
  fft32_stage<16>(ar, ai);
}

// |v|^(2*PE) * KS via native v_log_f32 + v_exp_f32. v=0 -> 0: ok.
__device__ __forceinline__ float pow_gain(float v, float PE, float KS) {
  return KS * __builtin_amdgcn_exp2f(PE * __builtin_amdgcn_logf(v));
}

__device__ __forceinline__ void denorm4(float4& r, float4& i, float PE, float KS) {
  float g;
  g = pow_gain(r.x * r.x + i.x * i.x, PE, KS); r.x *= g; i.x *= g;
  g = pow_gain(r.y * r.y + i.y * i.y, PE, KS); r.y *= g; i.y *= g;
  g = pow_gain(r.z * r.z + i.z * i.z, PE, KS); r.z *= g; i.z *= g;
  g = pow_gain(r.w * r.w + i.w * i.w, PE, KS); r.w *= g; i.w *= g;
}

// slot -> global row (slots 0..511; slot 512 is the explicit extra row).
// SC0: rows [0,256)+[768,1024); extra = row 256. SC1: rows [256,768);
// extra = row 768.
template <int SC>
__device__ __forceinline__ int slot_row(int s) {
  return (SC == 0) ? (s < 256 ? s : s + 512) : (s + 256);
}

// Pack a mirror pair: a = denormed S[rowa] (4 t's), b = S[1024-rowa].
// W[rowa]  = (Pre-u, Pim+v)   W[1024-rowa] = (Pre+u, v-Pim)
// T = e^{i pi rowa/1024}. Writes interleaved W to slots sa, sb (2 b128 each).
__device__ __forceinline__ void pack_pair_store(float* __restrict__ Sri,
    int sa, int sb, int cg, const float4& ar_, const float4& ai_,
    const float4& br_, const float4& bi_, int rowa) {
  const float ang = 3.0679615757712824e-3f * (float)rowa;
  const float ca = __cosf(ang), sn = __sinf(ang);
  const float arr[4] = {ar_.x, ar_.y, ar_.z, ar_.w};
  const float aii[4] = {ai_.x, ai_.y, ai_.z, ai_.w};
  const float brr[4] = {br_.x, br_.y, br_.z, br_.w};
  const float bii[4] = {bi_.x, bi_.y, bi_.z, bi_.w};
  float wa[8], wb[8];
  #pragma unroll
  for (int t = 0; t < 4; ++t) {
    const float Pre = arr[t] + brr[t], Pim = aii[t] - bii[t];
    const float Qre = arr[t] - brr[t], Qim = aii[t] + bii[t];
    const float u = ca * Qim + sn * Qre;
    const float v = ca * Qre - sn * Qim;
    wa[2*t] = Pre - u; wa[2*t+1] = Pim + v;
    wb[2*t] = Pre + u; wb[2*t+1] = v - Pim;
  }
  *(float4*)(Sri + sa * SSTR + 8 * cg)     = make_float4(wa[0], wa[1], wa[2], wa[3]);
  *(float4*)(Sri + sa * SSTR + 8 * cg + 4) = make_float4(wa[4], wa[5], wa[6], wa[7]);
  *(float4*)(Sri + sb * SSTR + 8 * cg)     = make_float4(wb[0], wb[1], wb[2], wb[3]);
  *(float4*)(Sri + sb * SSTR + 8 * cg + 4) = make_float4(wb[4], wb[5], wb[6], wb[7]);
}

// DC (k=0): Im of spec[0] dropped, Nyquist = 0 -> W[0] = re + i*re.
__device__ __forceinline__ void dc_store(float* __restrict__ Sri, int cg,
                                         const float4& r) {
  *(float4*)(Sri + 8 * cg)     = make_float4(r.x, r.x, r.y, r.y);
  *(float4*)(Sri + 8 * cg + 4) = make_float4(r.z, r.z, r.w, r.w);
}

// Consumer: read staged W for this thread's 16 k2's of superchunk SC.
// slot = q + 32u; row(slot) == q + 32*k2 by construction.
template <int SC>
__device__ __forceinline__ void stage1_read(const float* __restrict__ Sri,
                                            int q, int tl,
                                            float ar[32], float ai[32]) {
  #pragma unroll
  for (int u = 0; u < 16; ++u) {
    const int k2 = (SC == 0) ? (u < 8 ? u : u + 16) : (u + 8);
    const float2 w = *(const float2*)(Sri + (q + 32 * u) * SSTR + 2 * tl);
    ar[kBREV[k2]] = w.x; ai[kBREV[k2]] = w.y;
  }
}

// Full-X layout: X(t, k1, r) = k1*264 + r*8 + t (264 = 32*8 + 8 pad).
#define XIDX(t, k1, r) ((k1) * 264 + (r) * 8 + (t))
#define FSTR 2054               // frame tile row stride (even: float2 writes)

__global__ __launch_bounds__(256) void istft_fused(const float* __restrict__ in,
                                                   const float* __restrict__ invw,
                                                   float* __restrict__ out) {
  __shared__ float buf[16896];          // 67.6 KB, three overlapped tenants:
  float* Sri = buf;                     //  W staging: [0,10260)
  float* Xr  = buf;                     //  X full: [0,8448) + [8448,16896)
  float* Xi  = buf + 8448;
  float* Fh  = buf;                     //  frames: [0,16426)

  const int tid = threadIdx.x;
  const int tl  = tid & 7;              // t within tile
  const int q   = tid >> 3;             // k1 (stage 1) / r (stage 2)

  // XCD-aware remap (R8): each XCD owns 32 contiguous t-tiles of one batch.
  const int id   = blockIdx.x;          // 0..2047
  const int xcd  = id & 7;
  const int slot = id >> 3;             // 0..255
  const int b    = slot >> 5;           // 0..7
  const int tile = xcd * 32 + (slot & 31);  // 0..255
  const int t0   = tile * TT;

  const float* re_p = in + ((size_t)b * 2 + 0) * ((size_t)FDIM * TDIM);
  const float* im_p = in + ((size_t)b * 2 + 1) * ((size_t)FDIM * TDIM);

  const float KS = (float)(exp((-1.0 / 0.65) * log(0.06)) / 2048.0);
  const float PE = 7.0f / 26.0f;

  // mirror-pair slot set for this thread (exact cover of slots 0..512 with
  // in-thread pairs (c,512-c), (128+c,384-c); c=0 handles the specials).
  const int c  = tid >> 1;              // 0..127
  const int cg = tid & 1;               // t-quad
  int s_[4];
  if (c) { s_[0] = c; s_[1] = 512 - c; s_[2] = 128 + c; s_[3] = 384 - c; }
  else   { s_[0] = 0; s_[1] = 256;     s_[2] = 128;     s_[3] = 384;     }

  float ar[32], ai[32];

  // ---- Stage 1: pair-load A, denorm+pack+stage A; B loads in flight ----
  {
    float4 reA[4], imA[4];
    #pragma unroll
    for (int j = 0; j < 4; ++j) {
      const int row = slot_row<0>(s_[j]);
      reA[j] = *(const float4*)(re_p + (size_t)row * TDIM + t0 + 4 * cg);
      imA[j] = *(const float4*)(im_p + (size_t)row * TDIM + t0 + 4 * cg);
    }
    float4 exR, exI;                    // extra slot 512 = row 256 (tid<2)
    if (tid < 2) {
      exR = *(const float4*)(re_p + (size_t)256 * TDIM + t0 + 4 * tid);
      exI = *(const float4*)(im_p + (size_t)256 * TDIM + t0 + 4 * tid);
    }
    #pragma unroll
    for (int j = 0; j < 4; ++j) denorm4(reA[j], imA[j], PE, KS);
    if (tid < 2) denorm4(exR, exI, PE, KS);
    if (c) {
      pack_pair_store(Sri, s_[0], s_[1], cg, reA[0], imA[0], reA[1], imA[1], c);
      pack_pair_store(Sri, s_[2], s_[3], cg, reA[2], imA[2], reA[3], imA[3], 128 + c);
    } else {
      dc_store(Sri, cg, reA[0]);                                     // k=0
      pack_pair_store(Sri, 128, 384, cg, reA[2], imA[2], reA[3], imA[3], 128);
      pack_pair_store(Sri, 256, 512, cg, reA[1], imA[1], exR, exI, 768); // k=768/256
    }

    // issue superchunk B global loads now (consumed after read A)
    float4 reB[4], imB[4];
    #pragma unroll
    for (int j = 0; j < 4; ++j) {
      const int row = slot_row<1>(s_[j]);
      reB[j] = *(const float4*)(re_p + (size_t)row * TDIM + t0 + 4 * cg);
      imB[j] = *(const float4*)(im_p + (size_t)row * TDIM + t0 + 4 * cg);
    }
    float4 exRB, exIB;                  // extra slot 512 = row 768 (tid<2)
    if (tid < 2) {
      exRB = *(const float4*)(re_p + (size_t)768 * TDIM + t0 + 4 * tid);
      exIB = *(const float4*)(im_p + (size_t)768 * TDIM + t0 + 4 * tid);
    }
    __syncthreads();                    // staged W (A) visible

    stage1_read<0>(Sri, q, tl, ar, ai); // 16 b64, zero pack VALU
    __syncthreads();                    // all A reads done before B overwrites

    #pragma unroll
    for (int j = 0; j < 4; ++j) denorm4(reB[j], imB[j], PE, KS);
    if (tid < 2) denorm4(exRB, exIB, PE, KS);
    if (c) {
      pack_pair_store(Sri, s_[0], s_[1], cg, reB[0], imB[0], reB[1], imB[1], 256 + c);
      pack_pair_store(Sri, s_[2], s_[3], cg, reB[2], imB[2], reB[3], imB[3], 384 + c);
    } else {
      pack_pair_store(Sri, 0, 512, cg, reB[0], imB[0], exRB, exIB, 256); // k=256/768
      pack_pair_store(Sri, 128, 384, cg, reB[2], imB[2], reB[3], imB[3], 384);
      pack_pair_store(Sri, 256, 256, cg, reB[1], imB[1], reB[1], imB[1], 512); // k=512 self (Wa==Wb)
    }
    __syncthreads();                    // staged W (B) visible
    stage1_read<1>(Sri, q, tl, ar, ai);
    __syncthreads();                    // staging dead; X may overwrite buf
  }

  // ---- FFT32 over k2 ----
  ifft32_core(ar, ai);

  // ---- Transpose through FULL X: one write phase, one read phase (R14) ----
  // Inter-stage twiddle e^{2 pi i q r/1024} by incremental rotation
  // (31-step recurrence err ~2e-6, negligible vs absmax threshold).
  {
    const float aq2 = 6.1359231515425649e-3f * (float)q;
    const float dc = __cosf(aq2), dsn = __sinf(aq2);
    float cs = 1.0f, sn = 0.0f;
    #pragma unroll
    for (int r = 0; r < 32; ++r) {
      Xr[XIDX(tl, q, r)] = cs * ar[r] - sn * ai[r];
      Xi[XIDX(tl, q, r)] = cs * ai[r] + sn * ar[r];
      const float ncs = cs * dc - sn * dsn;
      sn = cs * dsn + sn * dc;
      cs = ncs;
    }
  }
  __syncthreads();
  float zr[32], zi[32];
  #pragma unroll
  for (int i = 0; i < 32; ++i) {        // bit-reversed k1 load order
    zr[i] = Xr[XIDX(tl, kBREV[i], q)];
    zi[i] = Xi[XIDX(tl, kBREV[i], q)];
  }
  __syncthreads();                      // X dead; F tile may overwrite buf

  // ---- Stage 2: FFT32 over k1 ----
  ifft32_core(zr, zi);

  // ---- Full 8-frame tile (all threads active) + single-pass OLA (R14) ----
  #pragma unroll
  for (int s = 0; s < 32; ++s) {
    const int l0 = 2 * q + 64 * s;
    const float2 w2 = *(const float2*)(invw + l0);
    float2 fv; fv.x = zr[s] * w2.x; fv.y = zi[s] * w2.y;
    *(float2*)(Fh + tl * FSTR + l0) = fv;
  }
  __syncthreads();

  // ---- OLA: out[512*t' + j] = sum_c F[t'-c-t0][j + 512c] ----
  float* ob = out + (size_t)b * NTOT;
  for (int rel = 0; rel < 11; ++rel) {
    const int tp = t0 + rel;
    if (tp > 2047) break;
    #pragma unroll
    for (int half = 0; half < 2; ++half) {
      const int j = tid + 256 * half;   // lanes j-consecutive -> coalesced
      float v = 0.0f;
      #pragma unroll
      for (int cc = 0; cc < 4; ++cc) {
        const int tt = rel - cc;
        if (tt >= 0 && tt < TT) v += Fh[tt * FSTR + j + 512 * cc];
      }
      const int n = tp * 512 + j;
      if (rel >= 3 && rel <= 7) ob[n] = v;          // all 4 contributors in-block
      else atomicAdd(&ob[n], v);                     // tile boundary: 2 writers
    }
  }
}

extern "C" void kernel_launch(void* const* d_in, const int* in_sizes, int n_in,
                              void* d_out, int out_size, void* d_ws, size_t ws_size,
                              hipStream_t stream) {
  (void)in_sizes; (void)n_in; (void)d_ws; (void)ws_size;
  const float* in   = (const float*)d_in[0];
  const float* invw = (const float*)d_in[1];
  float* out = (float*)d_out;
  hipMemsetAsync(out, 0, (size_t)out_size * sizeof(float), stream);
  istft_fused<<<dim3(TDIM / TT * 8), 256, 0, stream>>>(in, invw, out);
}